// Round 13
// baseline (5181.875 us; speedup 1.0000x reference)
//
#include <hip/hip_runtime.h>
#include <hip/hip_bf16.h>
#include <cstdint>
#include <cstddef>

typedef unsigned short u16;
typedef unsigned long long u64;
typedef __attribute__((ext_vector_type(8))) _Float16 h8;
typedef __attribute__((ext_vector_type(4))) float f32x4;
typedef __attribute__((ext_vector_type(4))) unsigned u32x4;

// ---------------- constants ----------------
#define NB 32          // batch
#define NT 1024        // time steps
#define NH 1024        // hidden
#define TCH 128        // base time chunk (k_gemm tile unit)
#define NCH 8          // number of base chunks

// workspace offsets (bytes). DSTRIDE_* are in ELEMENTS (u16); bytes = 2x.
#define O_XB   0ull                 // x fp16: 64MB
#define O_WIH  67108864ull          // wih fp16 both dirs: 16MB
#define O_WHHP 83886080ull          // whh packed fp16 frag-linear: 16MB (32MB slot)
#define O_BIAS 117440512ull         // bias sums f32: 32KB
#define O_HBUF 117473280ull         // h images: 4 groups x 2 bufs x 32KB = 256KB
#define O_CST  117735424ull         // c state f32 [dir][b][j]: 256KB
#define O_FLG  117997568ull         // flags: 4 grp x 64 producers x 128B = 32KB
#define O_GX   118030336ull         // Gx fp16: 64 / 128 / 256 / 512 MB
#define DSTRIDE_CH   16777216ull    // elems per dir (128-step chunk)
#define DSTRIDE_HALF 33554432ull    // elems per dir (256-step chunk)
#define DSTRIDE_Q    67108864ull    // elems per dir (512-step chunk)
#define DSTRIDE_FULL 134217728ull   // elems per dir (full 1024)
#define WS_NEED_HALF (O_GX + 2ull * DSTRIDE_HALF * 2ull)   // 252,248,064
#define WS_NEED_Q    (O_GX + 2ull * DSTRIDE_Q    * 2ull)   // 386,465,792
#define WS_NEED_FULL (O_GX + 2ull * DSTRIDE_FULL * 2ull)   // 654,901,248

__device__ __forceinline__ u16 f2h(float f){
  union { _Float16 h; u16 u; } v; v.h = (_Float16)f; return v.u;
}
__device__ __forceinline__ float h2f(u16 b){
  union { u16 u; _Float16 h; } v; v.u = b; return (float)v.h;
}
__device__ __forceinline__ float sig_f(float x){ return 1.0f / (1.0f + __expf(-x)); }
__device__ __forceinline__ float tanh_f(float x){ return 1.0f - 2.0f / (1.0f + __expf(2.0f * x)); }

// non-temporal scalar load (evict-first: gx is read exactly once — keep LLC for h images)
__device__ __forceinline__ u16 ldg_nt(const u16* p){
  return __builtin_nontemporal_load(p);
}

// plain global->LDS DMA (L2-cached) — used by k_gemm
__device__ __forceinline__ void g2l16(const void* g, void* l){
  __builtin_amdgcn_global_load_lds(
      (const __attribute__((address_space(1))) unsigned int*)g,
      (__attribute__((address_space(3))) unsigned int*)l, 16, 0, 0);
}
// coherent global->LDS DMA: aux = SC0|SC1 -> bypass L0+L2, read at LLC
__device__ __forceinline__ void g2l16c(const void* g, void* l){
  __builtin_amdgcn_global_load_lds(
      (const __attribute__((address_space(1))) unsigned int*)g,
      (__attribute__((address_space(3))) unsigned int*)l, 16, 0, 17);
}
// coherent 16B store (write-through to LLC)
__device__ __forceinline__ void store16_llc(void* p, u32x4 v){
  asm volatile("global_store_dwordx4 %0, %1, off sc0 sc1"
               :: "v"((unsigned long long)(uintptr_t)p), "v"(v) : "memory");
}

__device__ __forceinline__ float sel4(float s0, float s1, float s2, float s3, int k){
  float a = (k & 1) ? s1 : s0;
  float b = (k & 1) ? s3 : s2;
  return (k & 2) ? b : a;
}

// image byte offset for (row lr in 0..15, pre-swizzle byte bo in 0..2047)
__device__ __forceinline__ int img_off(int lr, int bo){
  return lr * 2048 + (bo ^ ((((lr & 7) ^ ((bo >> 8) & 7))) << 4));
}

// ---------------- f32 -> fp16 convert ----------------
__global__ void k_cvt(const float* __restrict__ src, u16* __restrict__ dst, int n){
  int i = (blockIdx.x * blockDim.x + threadIdx.x) * 4;
  int stride = gridDim.x * blockDim.x * 4;
  for (; i < n; i += stride){
    float4 v = *(const float4*)(src + i);
    uint2 p;
    p.x = (unsigned)f2h(v.x) | ((unsigned)f2h(v.y) << 16);
    p.y = (unsigned)f2h(v.z) | ((unsigned)f2h(v.w) << 16);
    *(uint2*)(dst + i) = p;
  }
}

// ---------------- pack Whh into fp16 fragment-linear layout ----------------
// frag index = ((dir*128 + jg)*2 + ni)*32 + ks ; 1024B per frag (lane*16B)
// lane c=lane&15 -> weight row n = (c>>2)*1024 + jg*8 + ni*4 + (c&3); k-chunk (lane>>4)*8
__global__ void k_pack_whh(const float* __restrict__ whh_f, const float* __restrict__ whh_r,
                           u16* __restrict__ dst){
  int bx = blockIdx.x;              // 512 blocks: dir*256 + jg*2 + ni
  int dir = bx >> 8, rem = bx & 255;
  int jg = rem >> 1, ni = rem & 1;
  const float* whh = dir ? whh_r : whh_f;
  int tid = threadIdx.x;
  int lane = tid & 63, wq = tid >> 6;
  int c = lane & 15;
  int n = (c >> 2) * 1024 + jg * 8 + ni * 4 + (c & 3);
  int kkb = (lane >> 4) * 8;
  size_t fb = (((size_t)dir * 128 + jg) * 2 + ni) * 32;
  for (int q = 0; q < 8; q++){
    int ks = wq * 8 + q;
    const float4* p = (const float4*)(whh + (size_t)n * 1024 + ks * 32 + kkb);
    float4 w0 = p[0], w1 = p[1];
    float w[8] = {w0.x, w0.y, w0.z, w0.w, w1.x, w1.y, w1.z, w1.w};
    unsigned hh[4];
    #pragma unroll
    for (int e = 0; e < 4; e++)
      hh[e] = (unsigned)f2h(w[2*e]) | ((unsigned)f2h(w[2*e+1]) << 16);
    uint4* dh = (uint4*)(dst + (fb + (size_t)ks) * 512 + lane * 8);
    *dh = make_uint4(hh[0], hh[1], hh[2], hh[3]);
  }
}

// ---------------- init: bias sums, h0 -> swizzled fp16 images, c state, flags ----
__global__ void k_init(const float* __restrict__ h0, const float* __restrict__ c0,
                       const float* __restrict__ bih_f, const float* __restrict__ bhh_f,
                       const float* __restrict__ bih_r, const float* __restrict__ bhh_r,
                       char* __restrict__ hbuf, float* __restrict__ cst,
                       float* __restrict__ bias, int* __restrict__ flg){
  int i = blockIdx.x * blockDim.x + threadIdx.x;
  int stride = gridDim.x * blockDim.x;
  for (int k = i; k < 32768; k += stride){
    int b = k >> 10, j = k & 1023;
    int lr = b & 15, mhb = b >> 4;
    u16 v = f2h(h0[k]);
    int off = img_off(lr, 2 * j);
    *(u16*)(hbuf + (size_t)((0 * 2 + mhb) * 2) * 32768 + off) = v;  // dir 0
    *(u16*)(hbuf + (size_t)((1 * 2 + mhb) * 2) * 32768 + off) = v;  // dir 1
    float cv = c0[k];
    cst[k] = cv;            // dir0
    cst[32768 + k] = cv;    // dir1
  }
  for (int k = i; k < 8192; k += stride){
    if (k < 4096) bias[k] = bih_f[k] + bhh_f[k];
    else          bias[k] = bih_r[k - 4096] + bhh_r[k - 4096];
  }
  for (int k = i; k < 8192; k += stride) flg[k] = 0;   // 4 grp x 64 x 32 ints
}

// ---------------- Phase 1: Gx = x @ Wih^T + bias (fp16), store permuted ----------------
// grid (32, 32, 2). chunk in 128-step units; tOff = local t offset in gx.
// gx stores are NON-TEMPORAL: written once, read once — keep LLC for h images.
__global__ __launch_bounds__(256, 2) void k_gemm(const u16* __restrict__ xb,
                                                 const u16* __restrict__ wih,
                                                 const float* __restrict__ bias,
                                                 u16* __restrict__ gx, int chunk,
                                                 int tOff, size_t dirStride){
  __shared__ u16 smem[2 * 16384]; // 2 x 32KB frag-linear, frag f at f*512 u16; A:0..15 B:16..31
  const int tid = threadIdx.x;
  const int lane = tid & 63, wid = tid >> 6;
  const int mi = wid >> 1, ni = wid & 1;
  const int c = lane & 15, rg = lane >> 4;
  const int n0 = blockIdx.x * 128;
  const int m0 = blockIdx.y * 128;        // rows m = tl*32 + bb
  const int dir = blockIdx.z;
  const u16* wd = wih + (size_t)dir * 4194304;

  f32x4 acc[4][4] = {};

  auto stage = [&](int buf, int k0){
    #pragma unroll
    for (int q = 0; q < 8; q++){
      int f = wid * 8 + q;
      int ks = f & 1;
      int kk = k0 + ks * 32 + rg * 8;
      const u16* src;
      if (f < 16){
        int rowloc = (f >> 1) * 16 + c;   // tile row 0..127
        int tl = (m0 + rowloc) >> 5;      // local t within 128-step chunk
        int bb = rowloc & 31;             // batch
        int tg = dir ? (1023 - chunk * TCH - tl) : (chunk * TCH + tl);
        src = xb + (size_t)(bb * 1024 + tg) * 1024 + kk;
      } else {
        int nt = (f - 16) >> 1;
        src = wd + (size_t)(n0 + nt * 16 + c) * 1024 + kk;
      }
      g2l16((const void*)src, (void*)(smem + buf * 16384 + f * 512));
    }
  };

  stage(0, 0);
  asm volatile("s_waitcnt vmcnt(0)" ::: "memory");
  __syncthreads();

  for (int it = 0; it < 16; it++){
    int cur = it & 1;
    if (it < 15) stage(cur ^ 1, (it + 1) * 64);
    const u16* bp = smem + cur * 16384;
    #pragma unroll
    for (int ks = 0; ks < 2; ks++){
      h8 a[4], b[4];
      #pragma unroll
      for (int im = 0; im < 4; im++)
        a[im] = *(const h8*)(bp + ((mi * 4 + im) * 2 + ks) * 512 + lane * 8);
      #pragma unroll
      for (int in_ = 0; in_ < 4; in_++)
        b[in_] = *(const h8*)(bp + 8192 + ((ni * 4 + in_) * 2 + ks) * 512 + lane * 8);
      #pragma unroll
      for (int im = 0; im < 4; im++)
        #pragma unroll
        for (int in_ = 0; in_ < 4; in_++)
          acc[im][in_] = __builtin_amdgcn_mfma_f32_16x16x32_f16(a[im], b[in_], acc[im][in_], 0, 0, 0);
    }
    asm volatile("s_waitcnt vmcnt(0)" ::: "memory");
    __syncthreads();
  }

  // epilogue: bias add, transpose via LDS, 16B vectorized permuted NT stores
  u16* T = (u16*)smem;                    // [128][128] fp16 tile
  const float* bd = bias + dir * 4096;
  #pragma unroll
  for (int in_ = 0; in_ < 4; in_++){
    int nnLocal = (ni * 4 + in_) * 16 + c;
    float bv = bd[n0 + nnLocal];
    #pragma unroll
    for (int im = 0; im < 4; im++){
      #pragma unroll
      for (int r = 0; r < 4; r++){
        int row = (mi * 4 + im) * 16 + rg * 4 + r;
        T[row * 128 + nnLocal] = f2h(acc[im][in_][r] + bv);
      }
    }
  }
  __syncthreads();
  u16* gxd = gx + (size_t)dir * dirStride;
  const int nprBase = ((n0 & 1023) >> 3) * 32 + ((n0 >> 10) << 3);
  #pragma unroll
  for (int q = 0; q < 8; q++){
    int flat = q * 256 + tid;
    int row = flat >> 4, c16 = flat & 15;
    u32x4 v = *(const u32x4*)(T + row * 128 + c16 * 8);
    __builtin_nontemporal_store(v,
        (u32x4*)(gxd + (size_t)(tOff * 32 + m0 + row) * 4096 + nprBase + c16 * 32));
  }
}

// ---------------- Phase 2: recurrent kernel (r10 geometry, fp16 weights) ----------------
// 256 blocks x 256 thr (4 waves), 1 block/CU. bx: dir=bx>>7; mh=(bx>>6)&1; ug=bx&63.
// 4 groups (dir,mh) of 64 blocks; block owns 16 units x 16 batch rows. Single fp16
// B-frag set: 32 MFMA/wave (2 parity chains). gx reads are NON-TEMPORAL (read-once
// streaming was evicting the 256KB h-image hot set from LLC -> ~96MB/dispatch of
// 900-cyc HBM misses on the recurrent critical chain; FETCH 240MB vs 144MB cold).
// Roles: wave0 {poll producers 0-31 -> DMA bytes [0,1024)/row -> drain -> lflag0},
// wave1 {producers 32-63, bytes [1024,2048) -> lflag1}, wave3 {after tb-sync:
// 32x16B stores + drain + producer flag}, wave2 free.
__global__ __launch_bounds__(256, 1) void k_rnn(const u16* __restrict__ gx,
                                                const u16* __restrict__ whhp,
                                                char* __restrict__ hbuf,
                                                float* __restrict__ cstate,
                                                float* __restrict__ dout,
                                                int* __restrict__ flg,
                                                int s0, int bar0, int nsteps,
                                                size_t dirStride){
  __shared__ char smem[32768];                 // h image for (dir,mh): 16 rows x 2048B
  __shared__ __align__(16) u16 tb[16][16];     // h_new transpose buffer [row][unit]
  __shared__ int lflag[2];                     // LDS ready flags for half0/half1
  const int tid = threadIdx.x;
  const int lane = tid & 63, wid = tid >> 6;
  const int bx = blockIdx.x;
  const int dir = bx >> 7, mh = (bx >> 6) & 1, ug = bx & 63;
  const int grp = dir * 2 + mh;
  const int c = lane & 15, rg = lane >> 4;
  const int g = c >> 2, jj = c & 3;
  const int u = ug * 16 + wid * 4 + jj;        // hidden unit for this lane's column
  const int jg = ug * 2 + (wid >> 1), ni = wid & 1;

  // --- Whh fragments into registers (single fp16 set; cached loads — reused
  //     across chunk dispatches, keep in LLC) ---
  h8 Bh[32];
  {
    size_t fb = (((size_t)dir * 128 + jg) * 2 + ni) * 32;
    #pragma unroll
    for (int ks = 0; ks < 32; ks++)
      Bh[ks] = *(const h8*)(whhp + (fb + ks) * 512 + lane * 8);
  }

  // --- c state: rows B = mh*16 + rg*4 + r ---
  float cst[4];
  #pragma unroll
  for (int r = 0; r < 4; r++)
    cst[r] = cstate[(size_t)dir * 32768 + (size_t)(mh * 16 + rg * 4 + r) * 1024 + u];

  const int npr = (u >> 3) * 32 + g * 8 + (u & 7);
  int* flags = flg + grp * 2048;               // 64 producers x 32 ints (128B lines)

  if (tid == 0){ lflag[0] = 0; lflag[1] = 0; }
  __syncthreads();

  // gx for t=0 (non-temporal)
  u16 gxu[4];
  {
    const size_t gof = (size_t)dir * dirStride + npr;
    #pragma unroll
    for (int r = 0; r < 4; r++)
      gxu[r] = ldg_nt(gx + gof + (size_t)(mh * 16 + rg * 4 + r) * 4096);
  }

  for (int t = 0; t < nsteps; t++){
    const int s = s0 + t;
    const char* img_r = hbuf + (size_t)(grp * 2 + (s & 1)) * 32768;
    char* img_w = hbuf + (size_t)(grp * 2 + ((s + 1) & 1)) * 32768;
    const unsigned tgt = (unsigned)(bar0 + t);

    // --- staging roles ---
    if (wid == 0){
      if (t > 0){
        int* fp = flags + (lane & 31) * 32;        // producers 0..31 (units 0..511)
        while (true){
          int v = __hip_atomic_load(fp, __ATOMIC_RELAXED, __HIP_MEMORY_SCOPE_AGENT);
          if (__all((unsigned)v >= tgt)) break;
        }
        asm volatile("" ::: "memory");
      }
      #pragma unroll
      for (int i = 0; i < 16; i++)                 // rows 0..15, bytes [0,1024)
        g2l16c(img_r + i * 2048 + lane * 16, smem + i * 2048 + lane * 16);
      asm volatile("s_waitcnt vmcnt(0)" ::: "memory");
      __hip_atomic_store(&lflag[0], t + 1, __ATOMIC_RELEASE, __HIP_MEMORY_SCOPE_WORKGROUP);
    } else if (wid == 1){
      if (t > 0){
        int* fp = flags + (32 + (lane & 31)) * 32; // producers 32..63 (units 512..1023)
        while (true){
          int v = __hip_atomic_load(fp, __ATOMIC_RELAXED, __HIP_MEMORY_SCOPE_AGENT);
          if (__all((unsigned)v >= tgt)) break;
        }
        asm volatile("" ::: "memory");
      }
      #pragma unroll
      for (int i = 0; i < 16; i++)                 // rows 0..15, bytes [1024,2048)
        g2l16c(img_r + i * 2048 + 1024 + lane * 16, smem + i * 2048 + 1024 + lane * 16);
      asm volatile("s_waitcnt vmcnt(0)" ::: "memory");
      __hip_atomic_store(&lflag[1], t + 1, __ATOMIC_RELEASE, __HIP_MEMORY_SCOPE_WORKGROUP);
    }

    // gx prefetch for t+1 (non-temporal): waves 0/1 after staging, 2/3 immediately
    u16 gxn[4];
    if (t < nsteps - 1){
      const size_t gof = (size_t)dir * dirStride + (size_t)(t + 1) * 131072 + npr;
      #pragma unroll
      for (int r = 0; r < 4; r++)
        gxn[r] = ldg_nt(gx + gof + (size_t)(mh * 16 + rg * 4 + r) * 4096);
    }

    // --- MFMA: 32 ks, 2 parity chains, split by K-half readiness ---
    f32x4 ae = {0.f,0.f,0.f,0.f}, ao = {0.f,0.f,0.f,0.f};
    const int abase = c * 2048;
    while (__hip_atomic_load(&lflag[0], __ATOMIC_ACQUIRE, __HIP_MEMORY_SCOPE_WORKGROUP) < t + 1) {}
    __builtin_amdgcn_sched_barrier(0);
    #pragma unroll
    for (int kp = 0; kp < 8; kp++){
      int b0 = (kp * 2) * 64 + rg * 16;
      int b1 = (kp * 2 + 1) * 64 + rg * 16;
      int ad0 = abase + (b0 ^ ((((c & 7) ^ ((b0 >> 8) & 7))) << 4));
      int ad1 = abase + (b1 ^ ((((c & 7) ^ ((b1 >> 8) & 7))) << 4));
      h8 x0 = *(const h8*)(smem + ad0);
      h8 x1 = *(const h8*)(smem + ad1);
      ae = __builtin_amdgcn_mfma_f32_16x16x32_f16(x0, Bh[kp * 2], ae, 0, 0, 0);
      ao = __builtin_amdgcn_mfma_f32_16x16x32_f16(x1, Bh[kp * 2 + 1], ao, 0, 0, 0);
    }
    while (__hip_atomic_load(&lflag[1], __ATOMIC_ACQUIRE, __HIP_MEMORY_SCOPE_WORKGROUP) < t + 1) {}
    __builtin_amdgcn_sched_barrier(0);
    #pragma unroll
    for (int kp = 8; kp < 16; kp++){
      int b0 = (kp * 2) * 64 + rg * 16;
      int b1 = (kp * 2 + 1) * 64 + rg * 16;
      int ad0 = abase + (b0 ^ ((((c & 7) ^ ((b0 >> 8) & 7))) << 4));
      int ad1 = abase + (b1 ^ ((((c & 7) ^ ((b1 >> 8) & 7))) << 4));
      h8 x0 = *(const h8*)(smem + ad0);
      h8 x1 = *(const h8*)(smem + ad1);
      ae = __builtin_amdgcn_mfma_f32_16x16x32_f16(x0, Bh[kp * 2], ae, 0, 0, 0);
      ao = __builtin_amdgcn_mfma_f32_16x16x32_f16(x1, Bh[kp * 2 + 1], ao, 0, 0, 0);
    }

    // --- elementwise LSTM cell (gate exchange via ds_swizzle xor 4/8/12) ---
    #pragma unroll
    for (int r = 0; r < 4; r++){
      float v = (ae[r] + ao[r]) + h2f(gxu[r]);
      float act = (g == 2) ? tanh_f(v) : sig_f(v);
      float a4  = __int_as_float(__builtin_amdgcn_ds_swizzle(__float_as_int(act), 0x101F));
      float a8  = __int_as_float(__builtin_amdgcn_ds_swizzle(__float_as_int(act), 0x201F));
      float a12 = __int_as_float(__builtin_amdgcn_ds_swizzle(__float_as_int(act), 0x301F));
      float i_s = sel4(act, a4, a8, a12, g);
      float f_s = sel4(act, a4, a8, a12, g ^ 1);
      float g_t = sel4(act, a4, a8, a12, g ^ 2);
      float o_s = sel4(act, a4, a8, a12, g ^ 3);
      float cn = f_s * cst[r] + i_s * g_t;
      cst[r] = cn;
      float hn = o_s * tanh_f(cn);
      if (g == 0){
        int lr = rg * 4 + r;
        tb[lr][wid * 4 + jj] = f2h(hn);
        if (s == 1023)
          dout[(size_t)dir * 32768 + (size_t)(mh * 16 + lr) * 1024 + u] = hn;
        if (t == nsteps - 1)
          cstate[(size_t)dir * 32768 + (size_t)(mh * 16 + lr) * 1024 + u] = cn;
      }
    }
    __syncthreads();   // tb complete; all waves finished MFMA -> smem reusable

    // --- h_new stores + producer flag: wave 3 only; waves 0-2 race ahead ---
    if (wid == 3){
      if (lane < 32){
        int lr = lane >> 1, half = lane & 1;
        u32x4 v = *(const u32x4*)&tb[lr][half * 8];
        store16_llc(img_w + img_off(lr, ug * 32 + half * 16), v);
      }
      asm volatile("s_waitcnt vmcnt(0)" ::: "memory");
      if (lane == 0 && t < nsteps - 1)
        __hip_atomic_store(&flags[ug * 32], bar0 + t + 1,
                           __ATOMIC_RELAXED, __HIP_MEMORY_SCOPE_AGENT);
    }

    if (t < nsteps - 1){
      #pragma unroll
      for (int r = 0; r < 4; r++) gxu[r] = gxn[r];
    }
  }
}

// ---------------- host launcher ----------------
extern "C" void kernel_launch(void* const* d_in, const int* in_sizes, int n_in,
                              void* d_out, int out_size, void* d_ws, size_t ws_size,
                              hipStream_t stream){
  const float* x     = (const float*)d_in[0];
  const float* h0    = (const float*)d_in[1];
  const float* c0    = (const float*)d_in[2];
  const float* Wih_f = (const float*)d_in[3];
  const float* Whh_f = (const float*)d_in[4];
  const float* bih_f = (const float*)d_in[5];
  const float* bhh_f = (const float*)d_in[6];
  const float* Wih_r = (const float*)d_in[7];
  const float* Whh_r = (const float*)d_in[8];
  const float* bih_r = (const float*)d_in[9];
  const float* bhh_r = (const float*)d_in[10];
  float* out = (float*)d_out;

  char* ws = (char*)d_ws;
  u16*   xb    = (u16*)(ws + O_XB);
  u16*   wih   = (u16*)(ws + O_WIH);
  u16*   whhp  = (u16*)(ws + O_WHHP);
  float* bias  = (float*)(ws + O_BIAS);
  char*  hbuf  = (char*)(ws + O_HBUF);
  float* cstw  = (float*)(ws + O_CST);
  int*   flg   = (int*)(ws + O_FLG);
  u16*   gx    = (u16*)(ws + O_GX);

  // conversions / packing / init (independent)
  k_cvt<<<2048, 256, 0, stream>>>(x, xb, 32 * 1024 * 1024);
  k_cvt<<<512, 256, 0, stream>>>(Wih_f, wih, 4096 * 1024);
  k_cvt<<<512, 256, 0, stream>>>(Wih_r, wih + 4194304, 4096 * 1024);
  k_pack_whh<<<512, 256, 0, stream>>>(Whh_f, Whh_r, whhp);
  k_init<<<64, 256, 0, stream>>>(h0, c0, bih_f, bhh_f, bih_r, bhh_r, hbuf, cstw, bias, flg);

  if (ws_size >= WS_NEED_FULL){
    for (int g = 0; g < NCH; g++)
      k_gemm<<<dim3(32, 32, 2), 256, 0, stream>>>(xb, wih, bias, gx, g,
                                                  g * TCH, (size_t)DSTRIDE_FULL);
    k_rnn<<<dim3(256), dim3(256), 0, stream>>>(gx, whhp, hbuf, cstw, out, flg,
                                               0, 0, NT, (size_t)DSTRIDE_FULL);
  } else if (ws_size >= WS_NEED_Q){
    // 2 chunks of 512 steps
    for (int c4 = 0; c4 < 2; c4++){
      for (int j = 0; j < 4; j++)
        k_gemm<<<dim3(32, 32, 2), 256, 0, stream>>>(xb, wih, bias, gx, 4 * c4 + j,
                                                    j * 128, (size_t)DSTRIDE_Q);
      k_rnn<<<dim3(256), dim3(256), 0, stream>>>(gx, whhp, hbuf, cstw, out, flg,
                                                 c4 * 512, c4 * 511, 512,
                                                 (size_t)DSTRIDE_Q);
    }
  } else if (ws_size >= WS_NEED_HALF){
    // 4 chunks of 256 steps
    for (int c2 = 0; c2 < 4; c2++){
      k_gemm<<<dim3(32, 32, 2), 256, 0, stream>>>(xb, wih, bias, gx, 2 * c2,
                                                  0, (size_t)DSTRIDE_HALF);
      k_gemm<<<dim3(32, 32, 2), 256, 0, stream>>>(xb, wih, bias, gx, 2 * c2 + 1,
                                                  128, (size_t)DSTRIDE_HALF);
      k_rnn<<<dim3(256), dim3(256), 0, stream>>>(gx, whhp, hbuf, cstw, out, flg,
                                                 c2 * 256, c2 * 255, 256,
                                                 (size_t)DSTRIDE_HALF);
    }
  } else {
    // 8 chunks of 128 steps (proven fallback)
    for (int ch = 0; ch < NCH; ch++){
      k_gemm<<<dim3(32, 32, 2), 256, 0, stream>>>(xb, wih, bias, gx, ch,
                                                  0, (size_t)DSTRIDE_CH);
      k_rnn<<<dim3(256), dim3(256), 0, stream>>>(gx, whhp, hbuf, cstw, out, flg,
                                                 ch * TCH, ch * (TCH - 1), TCH,
                                                 (size_t)DSTRIDE_CH);
    }
  }
}

// Round 14
// 4700.222 us; speedup vs baseline: 1.1025x; 1.1025x over previous
//
#include <hip/hip_runtime.h>
#include <hip/hip_bf16.h>
#include <cstdint>
#include <cstddef>

typedef unsigned short u16;
typedef unsigned long long u64;
typedef __attribute__((ext_vector_type(8))) _Float16 h8;
typedef __attribute__((ext_vector_type(4))) float f32x4;
typedef __attribute__((ext_vector_type(4))) unsigned u32x4;

// ---------------- constants ----------------
#define NB 32          // batch
#define NT 1024        // time steps
#define NH 1024        // hidden
#define TCH 128        // base time chunk (k_gemm tile unit)
#define NCH 8          // number of base chunks

// workspace offsets (bytes). DSTRIDE_* are in ELEMENTS (u16); bytes = 2x.
#define O_XB   0ull                 // x fp16: 64MB
#define O_WIH  67108864ull          // wih fp16 both dirs: 16MB
#define O_WHHP 83886080ull          // whh packed fp16 frag-linear: 16MB (32MB slot)
#define O_BIAS 117440512ull         // bias sums f32: 32KB
#define O_HBUF 117473280ull         // h images: 4 groups x 2 bufs x 32KB = 256KB
#define O_CST  117735424ull         // c state f32 [dir][b][j]: 256KB
#define O_FLG  117997568ull         // flags: 4 grp x 64 producers x 128B = 32KB
#define O_GX   118030336ull         // Gx fp16
#define DSTRIDE_CH   16777216ull    // elems per dir (128-step chunk)
#define DSTRIDE_HALF 33554432ull    // elems per dir (256-step chunk)
#define GXBUF_ELEMS  (2ull * DSTRIDE_HALF)                 // one 256-step buffer, both dirs
#define WS_NEED_HALF (O_GX + GXBUF_ELEMS * 2ull)           // 252,248,064
#define WS_NEED_DBUF (O_GX + 2ull * GXBUF_ELEMS * 2ull)    // 386,465,792 (known to fit)

__device__ __forceinline__ u16 f2h(float f){
  union { _Float16 h; u16 u; } v; v.h = (_Float16)f; return v.u;
}
__device__ __forceinline__ float h2f(u16 b){
  union { u16 u; _Float16 h; } v; v.u = b; return (float)v.h;
}
__device__ __forceinline__ float sig_f(float x){ return 1.0f / (1.0f + __expf(-x)); }
__device__ __forceinline__ float tanh_f(float x){ return 1.0f - 2.0f / (1.0f + __expf(2.0f * x)); }

// plain global->LDS DMA (L2-cached) — used by gemm role
__device__ __forceinline__ void g2l16(const void* g, void* l){
  __builtin_amdgcn_global_load_lds(
      (const __attribute__((address_space(1))) unsigned int*)g,
      (__attribute__((address_space(3))) unsigned int*)l, 16, 0, 0);
}
// coherent global->LDS DMA: aux = SC0|SC1 -> bypass L0+L2, read at LLC
__device__ __forceinline__ void g2l16c(const void* g, void* l){
  __builtin_amdgcn_global_load_lds(
      (const __attribute__((address_space(1))) unsigned int*)g,
      (__attribute__((address_space(3))) unsigned int*)l, 16, 0, 17);
}
// coherent 16B store (write-through to LLC)
__device__ __forceinline__ void store16_llc(void* p, u32x4 v){
  asm volatile("global_store_dwordx4 %0, %1, off sc0 sc1"
               :: "v"((unsigned long long)(uintptr_t)p), "v"(v) : "memory");
}

__device__ __forceinline__ float sel4(float s0, float s1, float s2, float s3, int k){
  float a = (k & 1) ? s1 : s0;
  float b = (k & 1) ? s3 : s2;
  return (k & 2) ? b : a;
}

// image byte offset for (row lr in 0..15, pre-swizzle byte bo in 0..2047)
__device__ __forceinline__ int img_off(int lr, int bo){
  return lr * 2048 + (bo ^ ((((lr & 7) ^ ((bo >> 8) & 7))) << 4));
}

// ---------------- f32 -> fp16 convert ----------------
__global__ void k_cvt(const float* __restrict__ src, u16* __restrict__ dst, int n){
  int i = (blockIdx.x * blockDim.x + threadIdx.x) * 4;
  int stride = gridDim.x * blockDim.x * 4;
  for (; i < n; i += stride){
    float4 v = *(const float4*)(src + i);
    uint2 p;
    p.x = (unsigned)f2h(v.x) | ((unsigned)f2h(v.y) << 16);
    p.y = (unsigned)f2h(v.z) | ((unsigned)f2h(v.w) << 16);
    *(uint2*)(dst + i) = p;
  }
}

// ---------------- pack Whh into fp16 fragment-linear layout ----------------
__global__ void k_pack_whh(const float* __restrict__ whh_f, const float* __restrict__ whh_r,
                           u16* __restrict__ dst){
  int bx = blockIdx.x;              // 512 blocks: dir*256 + jg*2 + ni
  int dir = bx >> 8, rem = bx & 255;
  int jg = rem >> 1, ni = rem & 1;
  const float* whh = dir ? whh_r : whh_f;
  int tid = threadIdx.x;
  int lane = tid & 63, wq = tid >> 6;
  int c = lane & 15;
  int n = (c >> 2) * 1024 + jg * 8 + ni * 4 + (c & 3);
  int kkb = (lane >> 4) * 8;
  size_t fb = (((size_t)dir * 128 + jg) * 2 + ni) * 32;
  for (int q = 0; q < 8; q++){
    int ks = wq * 8 + q;
    const float4* p = (const float4*)(whh + (size_t)n * 1024 + ks * 32 + kkb);
    float4 w0 = p[0], w1 = p[1];
    float w[8] = {w0.x, w0.y, w0.z, w0.w, w1.x, w1.y, w1.z, w1.w};
    unsigned hh[4];
    #pragma unroll
    for (int e = 0; e < 4; e++)
      hh[e] = (unsigned)f2h(w[2*e]) | ((unsigned)f2h(w[2*e+1]) << 16);
    uint4* dh = (uint4*)(dst + (fb + (size_t)ks) * 512 + lane * 8);
    *dh = make_uint4(hh[0], hh[1], hh[2], hh[3]);
  }
}

// ---------------- init: bias sums, h0 -> swizzled fp16 images, c state, flags ----
__global__ void k_init(const float* __restrict__ h0, const float* __restrict__ c0,
                       const float* __restrict__ bih_f, const float* __restrict__ bhh_f,
                       const float* __restrict__ bih_r, const float* __restrict__ bhh_r,
                       char* __restrict__ hbuf, float* __restrict__ cst,
                       float* __restrict__ bias, int* __restrict__ flg){
  int i = blockIdx.x * blockDim.x + threadIdx.x;
  int stride = gridDim.x * blockDim.x;
  for (int k = i; k < 32768; k += stride){
    int b = k >> 10, j = k & 1023;
    int lr = b & 15, mhb = b >> 4;
    u16 v = f2h(h0[k]);
    int off = img_off(lr, 2 * j);
    *(u16*)(hbuf + (size_t)((0 * 2 + mhb) * 2) * 32768 + off) = v;  // dir 0
    *(u16*)(hbuf + (size_t)((1 * 2 + mhb) * 2) * 32768 + off) = v;  // dir 1
    float cv = c0[k];
    cst[k] = cv;            // dir0
    cst[32768 + k] = cv;    // dir1
  }
  for (int k = i; k < 8192; k += stride){
    if (k < 4096) bias[k] = bih_f[k] + bhh_f[k];
    else          bias[k] = bih_r[k - 4096] + bhh_r[k - 4096];
  }
  for (int k = i; k < 8192; k += stride) flg[k] = 0;   // 4 grp x 64 x 32 ints
}

// ================= GEMM body (device) — r12-proven =================
// 128x128 tile, BK=64, frag-linear LDS (64KB), permuted 16B stores.
__device__ __forceinline__ void gemm_body(u16* smem,
                                          const u16* __restrict__ xb,
                                          const u16* __restrict__ wih,
                                          const float* __restrict__ bias,
                                          u16* __restrict__ gx, int chunk,
                                          int tOff, size_t dirStride,
                                          int bxp, int byp, int dir){
  const int tid = threadIdx.x;
  const int lane = tid & 63, wid = tid >> 6;
  const int mi = wid >> 1, ni = wid & 1;
  const int c = lane & 15, rg = lane >> 4;
  const int n0 = bxp * 128;
  const int m0 = byp * 128;               // rows m = tl*32 + bb
  const u16* wd = wih + (size_t)dir * 4194304;

  f32x4 acc[4][4] = {};

  auto stage = [&](int buf, int k0){
    #pragma unroll
    for (int q = 0; q < 8; q++){
      int f = wid * 8 + q;
      int ks = f & 1;
      int kk = k0 + ks * 32 + rg * 8;
      const u16* src;
      if (f < 16){
        int rowloc = (f >> 1) * 16 + c;   // tile row 0..127
        int tl = (m0 + rowloc) >> 5;      // local t within 128-step chunk
        int bb = rowloc & 31;             // batch
        int tg = dir ? (1023 - chunk * TCH - tl) : (chunk * TCH + tl);
        src = xb + (size_t)(bb * 1024 + tg) * 1024 + kk;
      } else {
        int nt = (f - 16) >> 1;
        src = wd + (size_t)(n0 + nt * 16 + c) * 1024 + kk;
      }
      g2l16((const void*)src, (void*)(smem + buf * 16384 + f * 512));
    }
  };

  stage(0, 0);
  asm volatile("s_waitcnt vmcnt(0)" ::: "memory");
  __syncthreads();

  for (int it = 0; it < 16; it++){
    int cur = it & 1;
    if (it < 15) stage(cur ^ 1, (it + 1) * 64);
    const u16* bp = smem + cur * 16384;
    #pragma unroll
    for (int ks = 0; ks < 2; ks++){
      h8 a[4], b[4];
      #pragma unroll
      for (int im = 0; im < 4; im++)
        a[im] = *(const h8*)(bp + ((mi * 4 + im) * 2 + ks) * 512 + lane * 8);
      #pragma unroll
      for (int in_ = 0; in_ < 4; in_++)
        b[in_] = *(const h8*)(bp + 8192 + ((ni * 4 + in_) * 2 + ks) * 512 + lane * 8);
      #pragma unroll
      for (int im = 0; im < 4; im++)
        #pragma unroll
        for (int in_ = 0; in_ < 4; in_++)
          acc[im][in_] = __builtin_amdgcn_mfma_f32_16x16x32_f16(a[im], b[in_], acc[im][in_], 0, 0, 0);
    }
    asm volatile("s_waitcnt vmcnt(0)" ::: "memory");
    __syncthreads();
  }

  // epilogue: bias add, transpose via LDS, 16B vectorized permuted stores
  u16* T = smem;                          // [128][128] fp16 tile
  const float* bd = bias + dir * 4096;
  #pragma unroll
  for (int in_ = 0; in_ < 4; in_++){
    int nnLocal = (ni * 4 + in_) * 16 + c;
    float bv = bd[n0 + nnLocal];
    #pragma unroll
    for (int im = 0; im < 4; im++){
      #pragma unroll
      for (int r = 0; r < 4; r++){
        int row = (mi * 4 + im) * 16 + rg * 4 + r;
        T[row * 128 + nnLocal] = f2h(acc[im][in_][r] + bv);
      }
    }
  }
  __syncthreads();
  u16* gxd = gx + (size_t)dir * dirStride;
  const int nprBase = ((n0 & 1023) >> 3) * 32 + ((n0 >> 10) << 3);
  #pragma unroll
  for (int q = 0; q < 8; q++){
    int flat = q * 256 + tid;
    int row = flat >> 4, c16 = flat & 15;
    u32x4 v = *(const u32x4*)(T + row * 128 + c16 * 8);
    *(u32x4*)(gxd + (size_t)(tOff * 32 + m0 + row) * 4096 + nprBase + c16 * 32) = v;
  }
}

__global__ __launch_bounds__(256, 2) void k_gemm(const u16* __restrict__ xb,
                                                 const u16* __restrict__ wih,
                                                 const float* __restrict__ bias,
                                                 u16* __restrict__ gx, int chunk,
                                                 int tOff, size_t dirStride){
  __shared__ u16 smem[2 * 16384];
  gemm_body(smem, xb, wih, bias, gx, chunk, tOff, dirStride,
            blockIdx.x, blockIdx.y, blockIdx.z);
}

// ================= RNN body (device) — r12-proven =================
// 256 rnn blocks x 256 thr (4 waves). rb: dir=rb>>7; mh=(rb>>6)&1; ug=rb&63.
// Single fp16 B-frag set: 32 MFMA/wave (2 parity chains). Wave-role pipeline.
__device__ __forceinline__ void rnn_body(char* smem, u16 (*tb)[16], int* lflag,
                                         const u16* __restrict__ gx,
                                         const u16* __restrict__ whhp,
                                         char* __restrict__ hbuf,
                                         float* __restrict__ cstate,
                                         float* __restrict__ dout,
                                         int* __restrict__ flg,
                                         int s0, int bar0, int nsteps,
                                         size_t dirStride, int rb){
  const int tid = threadIdx.x;
  const int lane = tid & 63, wid = tid >> 6;
  const int dir = rb >> 7, mh = (rb >> 6) & 1, ug = rb & 63;
  const int grp = dir * 2 + mh;
  const int c = lane & 15, rg = lane >> 4;
  const int g = c >> 2, jj = c & 3;
  const int u = ug * 16 + wid * 4 + jj;        // hidden unit for this lane's column
  const int jg = ug * 2 + (wid >> 1), ni = wid & 1;

  // --- Whh fragments into registers (single fp16 set) ---
  h8 Bh[32];
  {
    size_t fb = (((size_t)dir * 128 + jg) * 2 + ni) * 32;
    #pragma unroll
    for (int ks = 0; ks < 32; ks++)
      Bh[ks] = *(const h8*)(whhp + (fb + ks) * 512 + lane * 8);
  }

  // --- c state: rows B = mh*16 + rg*4 + r ---
  float cst[4];
  #pragma unroll
  for (int r = 0; r < 4; r++)
    cst[r] = cstate[(size_t)dir * 32768 + (size_t)(mh * 16 + rg * 4 + r) * 1024 + u];

  const int npr = (u >> 3) * 32 + g * 8 + (u & 7);
  int* flags = flg + grp * 2048;               // 64 producers x 32 ints (128B lines)

  if (tid == 0){ lflag[0] = 0; lflag[1] = 0; }
  __syncthreads();

  // gx for t=0
  u16 gxu[4];
  {
    const size_t gof = (size_t)dir * dirStride + npr;
    #pragma unroll
    for (int r = 0; r < 4; r++)
      gxu[r] = gx[gof + (size_t)(mh * 16 + rg * 4 + r) * 4096];
  }

  for (int t = 0; t < nsteps; t++){
    const int s = s0 + t;
    const char* img_r = hbuf + (size_t)(grp * 2 + (s & 1)) * 32768;
    char* img_w = hbuf + (size_t)(grp * 2 + ((s + 1) & 1)) * 32768;
    const unsigned tgt = (unsigned)(bar0 + t);

    // --- staging roles ---
    if (wid == 0){
      if (t > 0){
        int* fp = flags + (lane & 31) * 32;        // producers 0..31 (units 0..511)
        while (true){
          int v = __hip_atomic_load(fp, __ATOMIC_RELAXED, __HIP_MEMORY_SCOPE_AGENT);
          if (__all((unsigned)v >= tgt)) break;
        }
        asm volatile("" ::: "memory");
      }
      #pragma unroll
      for (int i = 0; i < 16; i++)                 // rows 0..15, bytes [0,1024)
        g2l16c(img_r + i * 2048 + lane * 16, smem + i * 2048 + lane * 16);
      asm volatile("s_waitcnt vmcnt(0)" ::: "memory");
      __hip_atomic_store(&lflag[0], t + 1, __ATOMIC_RELEASE, __HIP_MEMORY_SCOPE_WORKGROUP);
    } else if (wid == 1){
      if (t > 0){
        int* fp = flags + (32 + (lane & 31)) * 32; // producers 32..63 (units 512..1023)
        while (true){
          int v = __hip_atomic_load(fp, __ATOMIC_RELAXED, __HIP_MEMORY_SCOPE_AGENT);
          if (__all((unsigned)v >= tgt)) break;
        }
        asm volatile("" ::: "memory");
      }
      #pragma unroll
      for (int i = 0; i < 16; i++)                 // rows 0..15, bytes [1024,2048)
        g2l16c(img_r + i * 2048 + 1024 + lane * 16, smem + i * 2048 + 1024 + lane * 16);
      asm volatile("s_waitcnt vmcnt(0)" ::: "memory");
      __hip_atomic_store(&lflag[1], t + 1, __ATOMIC_RELEASE, __HIP_MEMORY_SCOPE_WORKGROUP);
    }

    // gx prefetch for t+1: waves 0/1 after staging, waves 2/3 immediately
    u16 gxn[4];
    if (t < nsteps - 1){
      const size_t gof = (size_t)dir * dirStride + (size_t)(t + 1) * 131072 + npr;
      #pragma unroll
      for (int r = 0; r < 4; r++)
        gxn[r] = gx[gof + (size_t)(mh * 16 + rg * 4 + r) * 4096];
    }

    // --- MFMA: 32 ks, 2 parity chains, split by K-half readiness ---
    f32x4 ae = {0.f,0.f,0.f,0.f}, ao = {0.f,0.f,0.f,0.f};
    const int abase = c * 2048;
    while (__hip_atomic_load(&lflag[0], __ATOMIC_ACQUIRE, __HIP_MEMORY_SCOPE_WORKGROUP) < t + 1) {}
    __builtin_amdgcn_sched_barrier(0);
    #pragma unroll
    for (int kp = 0; kp < 8; kp++){
      int b0 = (kp * 2) * 64 + rg * 16;
      int b1 = (kp * 2 + 1) * 64 + rg * 16;
      int ad0 = abase + (b0 ^ ((((c & 7) ^ ((b0 >> 8) & 7))) << 4));
      int ad1 = abase + (b1 ^ ((((c & 7) ^ ((b1 >> 8) & 7))) << 4));
      h8 x0 = *(const h8*)(smem + ad0);
      h8 x1 = *(const h8*)(smem + ad1);
      ae = __builtin_amdgcn_mfma_f32_16x16x32_f16(x0, Bh[kp * 2], ae, 0, 0, 0);
      ao = __builtin_amdgcn_mfma_f32_16x16x32_f16(x1, Bh[kp * 2 + 1], ao, 0, 0, 0);
    }
    while (__hip_atomic_load(&lflag[1], __ATOMIC_ACQUIRE, __HIP_MEMORY_SCOPE_WORKGROUP) < t + 1) {}
    __builtin_amdgcn_sched_barrier(0);
    #pragma unroll
    for (int kp = 8; kp < 16; kp++){
      int b0 = (kp * 2) * 64 + rg * 16;
      int b1 = (kp * 2 + 1) * 64 + rg * 16;
      int ad0 = abase + (b0 ^ ((((c & 7) ^ ((b0 >> 8) & 7))) << 4));
      int ad1 = abase + (b1 ^ ((((c & 7) ^ ((b1 >> 8) & 7))) << 4));
      h8 x0 = *(const h8*)(smem + ad0);
      h8 x1 = *(const h8*)(smem + ad1);
      ae = __builtin_amdgcn_mfma_f32_16x16x32_f16(x0, Bh[kp * 2], ae, 0, 0, 0);
      ao = __builtin_amdgcn_mfma_f32_16x16x32_f16(x1, Bh[kp * 2 + 1], ao, 0, 0, 0);
    }

    // --- elementwise LSTM cell (gate exchange via ds_swizzle xor 4/8/12) ---
    #pragma unroll
    for (int r = 0; r < 4; r++){
      float v = (ae[r] + ao[r]) + h2f(gxu[r]);
      float act = (g == 2) ? tanh_f(v) : sig_f(v);
      float a4  = __int_as_float(__builtin_amdgcn_ds_swizzle(__float_as_int(act), 0x101F));
      float a8  = __int_as_float(__builtin_amdgcn_ds_swizzle(__float_as_int(act), 0x201F));
      float a12 = __int_as_float(__builtin_amdgcn_ds_swizzle(__float_as_int(act), 0x301F));
      float i_s = sel4(act, a4, a8, a12, g);
      float f_s = sel4(act, a4, a8, a12, g ^ 1);
      float g_t = sel4(act, a4, a8, a12, g ^ 2);
      float o_s = sel4(act, a4, a8, a12, g ^ 3);
      float cn = f_s * cst[r] + i_s * g_t;
      cst[r] = cn;
      float hn = o_s * tanh_f(cn);
      if (g == 0){
        int lr = rg * 4 + r;
        tb[lr][wid * 4 + jj] = f2h(hn);
        if (s == 1023)
          dout[(size_t)dir * 32768 + (size_t)(mh * 16 + lr) * 1024 + u] = hn;
        if (t == nsteps - 1)
          cstate[(size_t)dir * 32768 + (size_t)(mh * 16 + lr) * 1024 + u] = cn;
      }
    }
    __syncthreads();   // tb complete; all waves finished MFMA -> smem reusable

    // --- h_new stores + producer flag: wave 3 only; waves 0-2 race ahead ---
    if (wid == 3){
      if (lane < 32){
        int lr = lane >> 1, half = lane & 1;
        u32x4 v = *(const u32x4*)&tb[lr][half * 8];
        store16_llc(img_w + img_off(lr, ug * 32 + half * 16), v);
      }
      asm volatile("s_waitcnt vmcnt(0)" ::: "memory");
      if (lane == 0 && t < nsteps - 1)
        __hip_atomic_store(&flags[ug * 32], bar0 + t + 1,
                           __ATOMIC_RELAXED, __HIP_MEMORY_SCOPE_AGENT);
    }

    if (t < nsteps - 1){
      #pragma unroll
      for (int r = 0; r < 4; r++) gxu[r] = gxn[r];
    }
  }
}

__global__ __launch_bounds__(256, 1) void k_rnn(const u16* __restrict__ gx,
                                                const u16* __restrict__ whhp,
                                                char* __restrict__ hbuf,
                                                float* __restrict__ cstate,
                                                float* __restrict__ dout,
                                                int* __restrict__ flg,
                                                int s0, int bar0, int nsteps,
                                                size_t dirStride){
  __shared__ char smem[32768];
  __shared__ __align__(16) u16 tb[16][16];
  __shared__ int lflag[2];
  rnn_body(smem, tb, lflag, gx, whhp, hbuf, cstate, dout, flg,
           s0, bar0, nsteps, dirStride, blockIdx.x);
}

// ================= Fused dispatch: rnn(chunk c) + gemm(chunk c+1) =================
// Blocks 0-255: rnn role (reads gxR). Blocks 256+: gemm role writing gxW for the
// NEXT 256-step chunk (4096 blocks = 2x (32x32x2)). One rnn + one gemm block
// co-resident per CU (LDS 66.5KB x2 = 133KB < 160; VGPR capped 256/wave).
// No deadlock: gemm blocks never wait on rnn -> they retire and free slots, so
// rnn's 256 blocks reach co-residency regardless of dispatch order.
__global__ __launch_bounds__(256, 2) void k_fused(const u16* __restrict__ xb,
                                                  const u16* __restrict__ wih,
                                                  const float* __restrict__ bias,
                                                  const u16* __restrict__ whhp,
                                                  char* __restrict__ hbuf,
                                                  float* __restrict__ cstate,
                                                  float* __restrict__ dout,
                                                  int* __restrict__ flg,
                                                  const u16* __restrict__ gxR,
                                                  u16* __restrict__ gxW,
                                                  int c256){
  __shared__ __align__(16) char S[65536 + 1024];
  const int bid = blockIdx.x;
  if (bid < 256){
    char* smem = S;
    u16 (*tb)[16] = (u16(*)[16])(S + 65536);
    int* lflag = (int*)(S + 65536 + 512);
    rnn_body(smem, tb, lflag, gxR, whhp, hbuf, cstate, dout, flg,
             c256 * 256, c256 * 255, 256, (size_t)DSTRIDE_HALF, bid);
  } else {
    int gid = bid - 256;                   // 0..4095
    int sub = gid >> 11;                   // which 128-step half of next chunk
    int rem = gid & 2047;
    int dir = rem >> 10;
    int r2  = rem & 1023;
    int byp = r2 >> 5, bxp = r2 & 31;
    gemm_body((u16*)S, xb, wih, bias, gxW,
              (c256 + 1) * 2 + sub, sub * 128, (size_t)DSTRIDE_HALF,
              bxp, byp, dir);
  }
}

// ---------------- host launcher ----------------
extern "C" void kernel_launch(void* const* d_in, const int* in_sizes, int n_in,
                              void* d_out, int out_size, void* d_ws, size_t ws_size,
                              hipStream_t stream){
  const float* x     = (const float*)d_in[0];
  const float* h0    = (const float*)d_in[1];
  const float* c0    = (const float*)d_in[2];
  const float* Wih_f = (const float*)d_in[3];
  const float* Whh_f = (const float*)d_in[4];
  const float* bih_f = (const float*)d_in[5];
  const float* bhh_f = (const float*)d_in[6];
  const float* Wih_r = (const float*)d_in[7];
  const float* Whh_r = (const float*)d_in[8];
  const float* bih_r = (const float*)d_in[9];
  const float* bhh_r = (const float*)d_in[10];
  float* out = (float*)d_out;

  char* ws = (char*)d_ws;
  u16*   xb    = (u16*)(ws + O_XB);
  u16*   wih   = (u16*)(ws + O_WIH);
  u16*   whhp  = (u16*)(ws + O_WHHP);
  float* bias  = (float*)(ws + O_BIAS);
  char*  hbuf  = (char*)(ws + O_HBUF);
  float* cstw  = (float*)(ws + O_CST);
  int*   flg   = (int*)(ws + O_FLG);
  u16*   gxA   = (u16*)(ws + O_GX);
  u16*   gxB   = gxA + GXBUF_ELEMS;

  // conversions / packing / init (independent)
  k_cvt<<<2048, 256, 0, stream>>>(x, xb, 32 * 1024 * 1024);
  k_cvt<<<512, 256, 0, stream>>>(Wih_f, wih, 4096 * 1024);
  k_cvt<<<512, 256, 0, stream>>>(Wih_r, wih + 4194304, 4096 * 1024);
  k_pack_whh<<<512, 256, 0, stream>>>(Whh_f, Whh_r, whhp);
  k_init<<<64, 256, 0, stream>>>(h0, c0, bih_f, bhh_f, bih_r, bhh_r, hbuf, cstw, bias, flg);

  if (ws_size >= WS_NEED_DBUF){
    // fused pipeline: gemm(0) alone, then {rnn(c) || gemm(c+1)} fused, rnn(3) alone
    k_gemm<<<dim3(32, 32, 2), 256, 0, stream>>>(xb, wih, bias, gxA, 0, 0, (size_t)DSTRIDE_HALF);
    k_gemm<<<dim3(32, 32, 2), 256, 0, stream>>>(xb, wih, bias, gxA, 1, 128, (size_t)DSTRIDE_HALF);
    for (int c = 0; c < 4; c++){
      const u16* gxR = (c & 1) ? gxB : gxA;
      u16*       gxW = (c & 1) ? gxA : gxB;
      int grid = 256 + (c < 3 ? 4096 : 0);
      k_fused<<<dim3(grid), dim3(256), 0, stream>>>(xb, wih, bias, whhp, hbuf, cstw,
                                                    out, flg, gxR, gxW, c);
    }
  } else if (ws_size >= WS_NEED_HALF){
    // r12-proven: 4 chunks of 256 steps, serial gemm+rnn
    for (int c2 = 0; c2 < 4; c2++){
      k_gemm<<<dim3(32, 32, 2), 256, 0, stream>>>(xb, wih, bias, gxA, 2 * c2,
                                                  0, (size_t)DSTRIDE_HALF);
      k_gemm<<<dim3(32, 32, 2), 256, 0, stream>>>(xb, wih, bias, gxA, 2 * c2 + 1,
                                                  128, (size_t)DSTRIDE_HALF);
      k_rnn<<<dim3(256), dim3(256), 0, stream>>>(gxA, whhp, hbuf, cstw, out, flg,
                                                 c2 * 256, c2 * 255, 256,
                                                 (size_t)DSTRIDE_HALF);
    }
  } else {
    // 8 chunks of 128 steps (proven fallback)
    for (int ch = 0; ch < NCH; ch++){
      k_gemm<<<dim3(32, 32, 2), 256, 0, stream>>>(xb, wih, bias, gxA, ch,
                                                  0, (size_t)DSTRIDE_CH);
      k_rnn<<<dim3(256), dim3(256), 0, stream>>>(gxA, whhp, hbuf, cstw, out, flg,
                                                 ch * TCH, ch * (TCH - 1), TCH,
                                                 (size_t)DSTRIDE_CH);
    }
  }
}